// Round 6
// baseline (781.001 us; speedup 1.0000x reference)
//
#include <hip/hip_runtime.h>
#include <hip/hip_bf16.h>

#define DIM 128
#define CAP 1536      // per-region staging capacity (mean 1024, +16 sigma)
#define RSTRIDE 16    // ints per region counter (64B anti-contention padding)

typedef __attribute__((ext_vector_type(8))) short bf16x8;
typedef __attribute__((ext_vector_type(4))) float f32x4;
typedef __attribute__((ext_vector_type(4))) unsigned uint4v;

__device__ inline unsigned short f2bf(float f) {
  union { float f; unsigned u; } v; v.f = f;
  return (unsigned short)((v.u + 0x7FFFu + ((v.u >> 16) & 1u)) >> 16);
}
__device__ inline float lo_f(unsigned u) {
  union { unsigned u; float f; } v; v.u = u << 16; return v.f;
}
__device__ inline float hi_f(unsigned u) {
  union { unsigned u; float f; } v; v.u = u & 0xFFFF0000u; return v.f;
}

// ---------------------------------------------------------------------------
// K1: partition edges into 64-node dst-regions. Entry = (dst&63)<<16 | src
// (src < 65536 holds for N=50000). Writes cluster at per-region frontiers ->
// dense cachelines -> ~4MB HBM writes instead of 55MB scattered.
// ---------------------------------------------------------------------------
__global__ __launch_bounds__(256) void partition_kernel(
    const int* __restrict__ ei, int* __restrict__ rptr,
    unsigned* __restrict__ staging, int E) {
  int e = blockIdx.x * 256 + threadIdx.x;
  if (e >= E) return;
  unsigned src = (unsigned)ei[e];
  int dst = ei[E + e];
  int r = dst >> 6;
  int slot = atomicAdd(&rptr[r * RSTRIDE], 1);
  if (slot < CAP) staging[(size_t)r * CAP + slot] = ((unsigned)(dst & 63) << 16) | src;
}

// ---------------------------------------------------------------------------
// K2: cast x -> bf16 into x-half of A with k-permutation: physical u32 j of a
// row holds logical dims (j, j+64). A row = 256 bf16: [0,128)=agg, [128,256)=x.
// ---------------------------------------------------------------------------
__global__ __launch_bounds__(256) void xcast_kernel(
    const float* __restrict__ x, unsigned* __restrict__ A_u32,
    int nnodes, int mpad) {
  int t = blockIdx.x * 256 + threadIdx.x;
  int node = t >> 6;
  if (node >= mpad) return;
  int j = t & 63;
  unsigned o = 0;
  if (node < nnodes) {
    float lo = x[(size_t)node * DIM + j];
    float hi = x[(size_t)node * DIM + 64 + j];
    o = (unsigned)f2bf(lo) | ((unsigned)f2bf(hi) << 16);
  }
  A_u32[(size_t)node * 128 + 64 + j] = o;
}

// ---------------------------------------------------------------------------
// K3: region aggregation. One block per 64-node region (== one MFMA m-tile).
// LDS f32 acc [64][129] (129-pad: ds_add bank = (row+col)&31 -> 2-way, free).
// Gathers bf16 x-rows (256B coalesced, readlane-broadcast src, 8-deep MLP),
// accumulates logical dims (lane, lane+64), counts degree, then
// normalize+cast+write agg-half of A (16B/lane coalesced stores).
// ---------------------------------------------------------------------------
__global__ __launch_bounds__(256) void regionagg_kernel(
    const int* __restrict__ rptr, const unsigned* __restrict__ staging,
    unsigned* __restrict__ A_u32) {
  __shared__ float acc[64][129];
  __shared__ int cnt_s[64];
  const int region = blockIdx.x;
  const int tid = threadIdx.x;

  for (int i = tid; i < 64 * 129; i += 256) ((float*)acc)[i] = 0.f;
  if (tid < 64) cnt_s[tid] = 0;
  __syncthreads();

  const int count = min(rptr[region * RSTRIDE], CAP);
  const size_t base = (size_t)region * CAP;
  const int w = tid >> 6, lane = tid & 63;
  const int e0 = (count * w) >> 2;
  const int e1 = (count * (w + 1)) >> 2;
  const unsigned* xs = A_u32 + 64 + lane;  // this lane's u32 within x-half

  for (int p = e0; p < e1; p += 64) {
    const int nv = min(64, e1 - p);
    unsigned ent = (p + lane < e1) ? staging[base + p + lane] : 0u;
    int i = 0;
    for (; i + 8 <= nv; i += 8) {
      int dw[8];
      unsigned uw[8];
#pragma unroll
      for (int k = 0; k < 8; ++k) {
        unsigned ek = (unsigned)__builtin_amdgcn_readlane((int)ent, i + k);
        dw[k] = (int)(ek >> 16);
        uw[k] = xs[(size_t)(ek & 0xFFFFu) * 128];
      }
#pragma unroll
      for (int k = 0; k < 8; ++k) {
        atomicAdd(&acc[dw[k]][lane], lo_f(uw[k]));
        atomicAdd(&acc[dw[k]][lane + 64], hi_f(uw[k]));
        if (lane == 0) atomicAdd(&cnt_s[dw[k]], 1);
      }
    }
    for (; i < nv; ++i) {
      unsigned ek = (unsigned)__builtin_amdgcn_readlane((int)ent, i);
      int d = (int)(ek >> 16);
      unsigned u = xs[(size_t)(ek & 0xFFFFu) * 128];
      atomicAdd(&acc[d][lane], lo_f(u));
      atomicAdd(&acc[d][lane + 64], hi_f(u));
      if (lane == 0) atomicAdd(&cnt_s[d], 1);
    }
  }
  __syncthreads();

  // epilogue: thread t -> row = t>>2, 16 u32s starting at jb=(t&3)*16
  const int row = tid >> 2;
  const int jb = (tid & 3) * 16;
  const float r = 1.0f / fmaxf((float)cnt_s[row], 1.0f);
  unsigned ov[16];
#pragma unroll
  for (int i2 = 0; i2 < 16; ++i2) {
    int j = jb + i2;
    ov[i2] = (unsigned)f2bf(acc[row][j] * r) |
             ((unsigned)f2bf(acc[row][j + 64] * r) << 16);
  }
  unsigned* dstp = A_u32 + (size_t)(region * 64 + row) * 128 + jb;
#pragma unroll
  for (int i2 = 0; i2 < 16; i2 += 4)
    *reinterpret_cast<uint4v*>(dstp + i2) = *reinterpret_cast<const uint4v*>(&ov[i2]);
}

// ---------------------------------------------------------------------------
// K4: pack B = [[Wl];[Wr]] (256x128) into MFMA fragment order, applying the
// same k-permutation as A: physical p within a half -> logical dim
// d = (p&1) ? (p>>1)+64 : (p>>1). Dot products are k-order invariant.
// ---------------------------------------------------------------------------
__global__ __launch_bounds__(256) void bpack_kernel(
    const float* __restrict__ Wl, const float* __restrict__ Wr,
    short* __restrict__ Bpack) {
  int t = blockIdx.x * 256 + threadIdx.x;
  if (t >= 4096) return;
  int lane = t & 63, nt = (t >> 6) & 7, ks = t >> 9;
  int c = nt * 16 + (lane & 15);
  int kb = ks * 32 + ((lane >> 4) << 3);
  bf16x8 o;
#pragma unroll
  for (int j = 0; j < 8; ++j) {
    int kk = kb + j;
    int p = kk & 127;
    int d = (p & 1) ? (p >> 1) + 64 : (p >> 1);
    float v = (kk < DIM) ? Wl[d * DIM + c] : Wr[d * DIM + c];
    o[j] = (short)f2bf(v);
  }
  reinterpret_cast<bf16x8*>(Bpack)[(ks * 8 + nt) * 64 + lane] = o;
}

// ---------------------------------------------------------------------------
// K5: MFMA GEMM + fused bias/relu/row-masked column-sum -> per-wave partials
// ---------------------------------------------------------------------------
__global__ __launch_bounds__(256) void mfma_kernel(
    const short* __restrict__ A, const short* __restrict__ Bpack,
    const float* __restrict__ bl, float* __restrict__ partial, int nnodes) {
  __shared__ short a_lds[64 * 256];
  const int tid = threadIdx.x;
  const int wave = tid >> 6, lane = tid & 63;
  const int mt = blockIdx.x;
  const size_t abase = (size_t)mt * 64 * 256;

#pragma unroll
  for (int r = 0; r < 8; ++r) {
    int i = tid + 256 * r;
    int row = i >> 5, kc = i & 31;
    bf16x8 v = *reinterpret_cast<const bf16x8*>(A + abase + row * 256 + kc * 8);
    int byte = (row * 512 + kc * 16) ^ ((row & 7) << 4);
    *reinterpret_cast<bf16x8*>(reinterpret_cast<char*>(a_lds) + byte) = v;
  }
  __syncthreads();

  f32x4 acc[8];
#pragma unroll
  for (int nt = 0; nt < 8; ++nt) acc[nt] = (f32x4){0.f, 0.f, 0.f, 0.f};

  const int arow = wave * 16 + (lane & 15);
  const int kgrp = lane >> 4;
  const bf16x8* Bp = reinterpret_cast<const bf16x8*>(Bpack);

#pragma unroll
  for (int ks = 0; ks < 8; ++ks) {
    int byte = (arow * 512 + (ks * 32 + kgrp * 8) * 2) ^ ((arow & 7) << 4);
    bf16x8 a = *reinterpret_cast<const bf16x8*>(reinterpret_cast<char*>(a_lds) + byte);
#pragma unroll
    for (int nt = 0; nt < 8; ++nt) {
      bf16x8 b = Bp[(ks * 8 + nt) * 64 + lane];
      acc[nt] = __builtin_amdgcn_mfma_f32_16x16x32_bf16(a, b, acc[nt], 0, 0, 0);
    }
  }

  const int col16 = lane & 15;
  const int rowbase = mt * 64 + wave * 16 + kgrp * 4;
#pragma unroll
  for (int nt = 0; nt < 8; ++nt) {
    const int c = nt * 16 + col16;
    const float bb = bl[c];
    float s = 0.f;
#pragma unroll
    for (int rg = 0; rg < 4; ++rg) {
      float v = fmaxf(acc[nt][rg] + bb, 0.f);
      s += (rowbase + rg < nnodes) ? v : 0.f;
    }
    s += __shfl_xor(s, 16);
    s += __shfl_xor(s, 32);
    if (kgrp == 0) partial[((size_t)mt * 4 + wave) * DIM + c] = s;
  }
}

// ---------------------------------------------------------------------------
// K6a: parallel row-reduction of partial [nrows][128] -> red[128][128]
// ---------------------------------------------------------------------------
__global__ __launch_bounds__(256) void red1_kernel(
    const float* __restrict__ partial, int nrows, float* __restrict__ red) {
  __shared__ float tmp[128];
  const int c = threadIdx.x & 127;
  const int half = threadIdx.x >> 7;
  const int chunk = (nrows + 127) / 128;
  const int r0 = blockIdx.x * chunk;
  const int r1 = min(r0 + chunk, nrows);
  float s = 0.f;
  for (int r = r0 + half; r < r1; r += 2) s += partial[(size_t)r * DIM + c];
  if (half) tmp[c] = s;
  __syncthreads();
  if (!half) red[(size_t)blockIdx.x * DIM + c] = s + tmp[c];
}

// ---------------------------------------------------------------------------
// K6b: sum red's 128 rows, dot with W_out, scale, add bias.
// ---------------------------------------------------------------------------
__global__ __launch_bounds__(256) void red2_kernel(
    const float* __restrict__ red, const float* __restrict__ Wout,
    const float* __restrict__ bout, float* __restrict__ out, int nnodes) {
  __shared__ float tmp[128];
  __shared__ float prod[128];
  const int c = threadIdx.x & 127;
  const int half = threadIdx.x >> 7;
  float s = 0.f;
  for (int r = half; r < 128; r += 2) s += red[(size_t)r * DIM + c];
  if (half) tmp[c] = s;
  __syncthreads();
  if (!half) prod[c] = (s + tmp[c]) * Wout[c];
  __syncthreads();
  if (threadIdx.x == 0) {
    float v = 0.f;
    for (int i = 0; i < 128; ++i) v += prod[i];
    out[0] = v / (float)nnodes + bout[0];
  }
}

extern "C" void kernel_launch(void* const* d_in, const int* in_sizes, int n_in,
                              void* d_out, int out_size, void* d_ws, size_t ws_size,
                              hipStream_t stream) {
  const float* x    = (const float*)d_in[0];   // x_ligand [N,128]
  const int*   ei   = (const int*)d_in[4];     // ei_ll [2,E]
  const float* Wl   = (const float*)d_in[11];  // Wl_ll [128,128]
  const float* bl   = (const float*)d_in[12];  // bl_ll [128]
  const float* Wr   = (const float*)d_in[13];  // Wr_ll [128,128]
  const float* Wout = (const float*)d_in[14];  // W_out [128,1]
  const float* bout = (const float*)d_in[15];  // b_out [1]

  const int nnodes = in_sizes[0] / DIM;
  const int E = in_sizes[4] / 2;
  const int mtiles = (nnodes + 63) / 64;   // 782 == #regions
  const int mpad = mtiles * 64;            // 50048

  // ws layout: [rptr mtiles*RSTRIDE ints][staging mtiles*CAP u32]
  //            [A mpad*256 bf16][Bpack 32768 bf16][red 128*128 f32]
  // partial (mtiles*4*128 f32 = 1.6MB) aliases staging (dead after regionagg).
  int*      rptr    = (int*)d_ws;
  unsigned* staging = (unsigned*)(rptr + (size_t)mtiles * RSTRIDE);
  short*    A       = (short*)(staging + (size_t)mtiles * CAP);
  short*    Bpack   = A + (size_t)mpad * 256;
  float*    red     = (float*)(Bpack + 32768);
  float*    partial = (float*)staging;  // alias
  unsigned* A_u32   = (unsigned*)A;

  hipMemsetAsync(rptr, 0, (size_t)mtiles * RSTRIDE * sizeof(int), stream);

  partition_kernel<<<(E + 255) / 256, 256, 0, stream>>>(ei, rptr, staging, E);

  bpack_kernel<<<16, 256, 0, stream>>>(Wl, Wr, Bpack);

  xcast_kernel<<<(mpad * 64 + 255) / 256, 256, 0, stream>>>(x, A_u32, nnodes, mpad);

  regionagg_kernel<<<mtiles, 256, 0, stream>>>(rptr, staging, A_u32);

  mfma_kernel<<<mtiles, 256, 0, stream>>>(A, Bpack, bl, partial, nnodes);

  red1_kernel<<<128, 256, 0, stream>>>(partial, mtiles * 4, red);
  red2_kernel<<<1, 256, 0, stream>>>(red, Wout, bout, (float*)d_out, nnodes);
}

// Round 7
// 134.584 us; speedup vs baseline: 5.8031x; 5.8031x over previous
//
#include <hip/hip_runtime.h>
#include <hip/hip_bf16.h>

#define DIM 128
#define CAP 1536      // per-region staging capacity (mean 1024, +16 sigma)
#define RSTRIDE 16    // ints per region counter (64B anti-contention padding)

typedef __attribute__((ext_vector_type(8))) short bf16x8;
typedef __attribute__((ext_vector_type(4))) float f32x4;
typedef __attribute__((ext_vector_type(4))) short short4v;

__device__ inline unsigned short f2bf(float f) {
  union { float f; unsigned u; } v; v.f = f;
  return (unsigned short)((v.u + 0x7FFFu + ((v.u >> 16) & 1u)) >> 16);
}
__device__ inline float lo_f(unsigned u) {
  union { unsigned u; float f; } v; v.u = u << 16; return v.f;
}
__device__ inline float hi_f(unsigned u) {
  union { unsigned u; float f; } v; v.u = u & 0xFFFF0000u; return v.f;
}

// ---------------------------------------------------------------------------
// K1: partition edges into 64-node dst-regions. Entry = (dst&63)<<16 | src
// (src < 65536 holds for N=50000). Frontier-bumped writes cluster into dense
// per-region windows (vs fill_kernel's 55MB of scattered 4B write-through).
// ---------------------------------------------------------------------------
__global__ __launch_bounds__(256) void partition_kernel(
    const int* __restrict__ ei, int* __restrict__ rptr,
    unsigned* __restrict__ staging, int E) {
  int e = blockIdx.x * 256 + threadIdx.x;
  if (e >= E) return;
  unsigned src = (unsigned)ei[e];
  int dst = ei[E + e];
  int r = dst >> 6;
  int slot = atomicAdd(&rptr[r * RSTRIDE], 1);
  if (slot < CAP) staging[(size_t)r * CAP + slot] = ((unsigned)(dst & 63) << 16) | src;
}

// ---------------------------------------------------------------------------
// K2: per-region in-LDS counting sort -> dst-sorted src lists (in place in
// staging, coalesced writeback) + per-node deg (cnt) and global offset (off).
// One block per region, ~1024 entries, 64 buckets.
// ---------------------------------------------------------------------------
__global__ __launch_bounds__(256) void compact_kernel(
    const int* __restrict__ rptr, unsigned* __restrict__ staging,
    int* __restrict__ cnt, int* __restrict__ off) {
  __shared__ unsigned raw[CAP];
  __shared__ unsigned sorted[CAP];
  __shared__ int h[64];
  __shared__ int start[64];
  __shared__ int fill[64];
  const int region = blockIdx.x;
  const int tid = threadIdx.x;
  const int count = min(rptr[region * RSTRIDE], CAP);
  const size_t base = (size_t)region * CAP;

  if (tid < 64) h[tid] = 0;
  __syncthreads();
  for (int i = tid; i < count; i += 256) {
    unsigned e = staging[base + i];
    raw[i] = e;
    atomicAdd(&h[e >> 16], 1);
  }
  __syncthreads();
  if (tid == 0) {
    int s = 0;
    for (int i = 0; i < 64; ++i) { start[i] = s; s += h[i]; }
  }
  if (tid < 64) fill[tid] = 0;
  __syncthreads();
  for (int i = tid; i < count; i += 256) {
    unsigned e = raw[i];
    int d = (int)(e >> 16);
    int pos = start[d] + atomicAdd(&fill[d], 1);
    sorted[pos] = e & 0xFFFFu;  // keep only src
  }
  __syncthreads();
  for (int i = tid; i < count; i += 256) staging[base + i] = sorted[i];
  if (tid < 64) {
    int node = region * 64 + tid;
    cnt[node] = h[tid];
    off[node] = (int)base + start[tid];
  }
}

// ---------------------------------------------------------------------------
// K3: cast x -> bf16 into the x-half of A.  A layout: [mpad][256] bf16,
// k<128 = agg (written by agg_kernel), k>=128 = x.
// ---------------------------------------------------------------------------
__global__ __launch_bounds__(256) void xcast_kernel(
    const float* __restrict__ x, short* __restrict__ A, int nnodes, int mpad) {
  int t = blockIdx.x * 256 + threadIdx.x;
  int node = t >> 5;
  if (node >= mpad) return;
  int c = (t & 31) * 4;
  short4v o = (short4v){0, 0, 0, 0};
  if (node < nnodes) {
    float4 v = *reinterpret_cast<const float4*>(x + (size_t)node * DIM + c);
    o.x = (short)f2bf(v.x); o.y = (short)f2bf(v.y);
    o.z = (short)f2bf(v.z); o.w = (short)f2bf(v.w);
  }
  *reinterpret_cast<short4v*>(A + (size_t)node * 256 + 128 + c) = o;
}

// ---------------------------------------------------------------------------
// K4: mean-aggregation, one wave per node (50048 waves of TLP); gathers bf16
// x-rows from A's x-half (256B coalesced, 4-deep MLP), writes bf16 agg into
// A's agg-half.
// ---------------------------------------------------------------------------
__global__ __launch_bounds__(256) void agg_kernel(
    const int* __restrict__ cnt, const int* __restrict__ off,
    const unsigned* __restrict__ bucket, short* __restrict__ A,
    int nnodes, int mpad) {
  const int wid = (blockIdx.x * 256 + threadIdx.x) >> 6;
  const int lane = threadIdx.x & 63;
  if (wid >= mpad) return;
  unsigned* dst = reinterpret_cast<unsigned*>(A + (size_t)wid * 256) + lane;
  if (wid >= nnodes) { *dst = 0u; return; }
  const int deg  = __builtin_amdgcn_readfirstlane(cnt[wid]);
  const int base = __builtin_amdgcn_readfirstlane(off[wid]);
  const unsigned* xs = reinterpret_cast<const unsigned*>(A) + 64 + lane;

  float a0 = 0.f, b0 = 0.f, a1 = 0.f, b1 = 0.f;
  float a2 = 0.f, b2 = 0.f, a3 = 0.f, b3 = 0.f;
  int j = 0;
  for (; j + 3 < deg; j += 4) {
    const int s0 = __builtin_amdgcn_readfirstlane((int)bucket[base + j]);
    const int s1 = __builtin_amdgcn_readfirstlane((int)bucket[base + j + 1]);
    const int s2 = __builtin_amdgcn_readfirstlane((int)bucket[base + j + 2]);
    const int s3 = __builtin_amdgcn_readfirstlane((int)bucket[base + j + 3]);
    unsigned u0 = xs[(size_t)s0 * 128];
    unsigned u1 = xs[(size_t)s1 * 128];
    unsigned u2 = xs[(size_t)s2 * 128];
    unsigned u3 = xs[(size_t)s3 * 128];
    a0 += lo_f(u0); b0 += hi_f(u0);
    a1 += lo_f(u1); b1 += hi_f(u1);
    a2 += lo_f(u2); b2 += hi_f(u2);
    a3 += lo_f(u3); b3 += hi_f(u3);
  }
  for (; j < deg; ++j) {
    const int s0 = __builtin_amdgcn_readfirstlane((int)bucket[base + j]);
    unsigned u0 = xs[(size_t)s0 * 128];
    a0 += lo_f(u0); b0 += hi_f(u0);
  }
  const float r = 1.0f / fmaxf((float)deg, 1.0f);
  const float av = (a0 + a1 + a2 + a3) * r;
  const float bv = (b0 + b1 + b2 + b3) * r;
  *dst = (unsigned)f2bf(av) | ((unsigned)f2bf(bv) << 16);
}

// ---------------------------------------------------------------------------
// K5: pack B = [[Wl];[Wr]] (256x128) into MFMA fragment order
// ---------------------------------------------------------------------------
__global__ __launch_bounds__(256) void bpack_kernel(
    const float* __restrict__ Wl, const float* __restrict__ Wr,
    short* __restrict__ Bpack) {
  int t = blockIdx.x * 256 + threadIdx.x;
  if (t >= 4096) return;
  int lane = t & 63, nt = (t >> 6) & 7, ks = t >> 9;
  int c = nt * 16 + (lane & 15);
  int kb = ks * 32 + ((lane >> 4) << 3);
  bf16x8 o;
#pragma unroll
  for (int j = 0; j < 8; ++j) {
    int k = kb + j;
    float v = (k < DIM) ? Wl[k * DIM + c] : Wr[(k - DIM) * DIM + c];
    o[j] = (short)f2bf(v);
  }
  reinterpret_cast<bf16x8*>(Bpack)[(ks * 8 + nt) * 64 + lane] = o;
}

// ---------------------------------------------------------------------------
// K6: MFMA GEMM + fused bias/relu/row-masked column-sum -> per-wave partials
// ---------------------------------------------------------------------------
__global__ __launch_bounds__(256) void mfma_kernel(
    const short* __restrict__ A, const short* __restrict__ Bpack,
    const float* __restrict__ bl, float* __restrict__ partial, int nnodes) {
  __shared__ short a_lds[64 * 256];
  const int tid = threadIdx.x;
  const int wave = tid >> 6, lane = tid & 63;
  const int mt = blockIdx.x;
  const size_t abase = (size_t)mt * 64 * 256;

#pragma unroll
  for (int r = 0; r < 8; ++r) {
    int i = tid + 256 * r;
    int row = i >> 5, kc = i & 31;
    bf16x8 v = *reinterpret_cast<const bf16x8*>(A + abase + row * 256 + kc * 8);
    int byte = (row * 512 + kc * 16) ^ ((row & 7) << 4);
    *reinterpret_cast<bf16x8*>(reinterpret_cast<char*>(a_lds) + byte) = v;
  }
  __syncthreads();

  f32x4 acc[8];
#pragma unroll
  for (int nt = 0; nt < 8; ++nt) acc[nt] = (f32x4){0.f, 0.f, 0.f, 0.f};

  const int arow = wave * 16 + (lane & 15);
  const int kgrp = lane >> 4;
  const bf16x8* Bp = reinterpret_cast<const bf16x8*>(Bpack);

#pragma unroll
  for (int ks = 0; ks < 8; ++ks) {
    int byte = (arow * 512 + (ks * 32 + kgrp * 8) * 2) ^ ((arow & 7) << 4);
    bf16x8 a = *reinterpret_cast<const bf16x8*>(reinterpret_cast<char*>(a_lds) + byte);
#pragma unroll
    for (int nt = 0; nt < 8; ++nt) {
      bf16x8 b = Bp[(ks * 8 + nt) * 64 + lane];
      acc[nt] = __builtin_amdgcn_mfma_f32_16x16x32_bf16(a, b, acc[nt], 0, 0, 0);
    }
  }

  const int col16 = lane & 15;
  const int rowbase = mt * 64 + wave * 16 + kgrp * 4;
#pragma unroll
  for (int nt = 0; nt < 8; ++nt) {
    const int c = nt * 16 + col16;
    const float bb = bl[c];
    float s = 0.f;
#pragma unroll
    for (int rg = 0; rg < 4; ++rg) {
      float v = fmaxf(acc[nt][rg] + bb, 0.f);
      s += (rowbase + rg < nnodes) ? v : 0.f;
    }
    s += __shfl_xor(s, 16);
    s += __shfl_xor(s, 32);
    if (kgrp == 0) partial[((size_t)mt * 4 + wave) * DIM + c] = s;
  }
}

// ---------------------------------------------------------------------------
// K7a: parallel row-reduction of partial [nrows][128] -> red[128][128]
// ---------------------------------------------------------------------------
__global__ __launch_bounds__(256) void red1_kernel(
    const float* __restrict__ partial, int nrows, float* __restrict__ red) {
  __shared__ float tmp[128];
  const int c = threadIdx.x & 127;
  const int half = threadIdx.x >> 7;
  const int chunk = (nrows + 127) / 128;
  const int r0 = blockIdx.x * chunk;
  const int r1 = min(r0 + chunk, nrows);
  float s = 0.f;
  for (int r = r0 + half; r < r1; r += 2) s += partial[(size_t)r * DIM + c];
  if (half) tmp[c] = s;
  __syncthreads();
  if (!half) red[(size_t)blockIdx.x * DIM + c] = s + tmp[c];
}

// ---------------------------------------------------------------------------
// K7b: sum red's 128 rows, dot with W_out, scale, add bias.
// ---------------------------------------------------------------------------
__global__ __launch_bounds__(256) void red2_kernel(
    const float* __restrict__ red, const float* __restrict__ Wout,
    const float* __restrict__ bout, float* __restrict__ out, int nnodes) {
  __shared__ float tmp[128];
  __shared__ float prod[128];
  const int c = threadIdx.x & 127;
  const int half = threadIdx.x >> 7;
  float s = 0.f;
  for (int r = half; r < 128; r += 2) s += red[(size_t)r * DIM + c];
  if (half) tmp[c] = s;
  __syncthreads();
  if (!half) prod[c] = (s + tmp[c]) * Wout[c];
  __syncthreads();
  if (threadIdx.x == 0) {
    float v = 0.f;
    for (int i = 0; i < 128; ++i) v += prod[i];
    out[0] = v / (float)nnodes + bout[0];
  }
}

extern "C" void kernel_launch(void* const* d_in, const int* in_sizes, int n_in,
                              void* d_out, int out_size, void* d_ws, size_t ws_size,
                              hipStream_t stream) {
  const float* x    = (const float*)d_in[0];   // x_ligand [N,128]
  const int*   ei   = (const int*)d_in[4];     // ei_ll [2,E]
  const float* Wl   = (const float*)d_in[11];  // Wl_ll [128,128]
  const float* bl   = (const float*)d_in[12];  // bl_ll [128]
  const float* Wr   = (const float*)d_in[13];  // Wr_ll [128,128]
  const float* Wout = (const float*)d_in[14];  // W_out [128,1]
  const float* bout = (const float*)d_in[15];  // b_out [1]

  const int nnodes = in_sizes[0] / DIM;
  const int E = in_sizes[4] / 2;
  const int mtiles = (nnodes + 63) / 64;   // 782 == #regions
  const int mpad = mtiles * 64;            // 50048

  // ws layout: [rptr mtiles*RSTRIDE][cnt mpad][off mpad][staging mtiles*CAP u32]
  //            [A mpad*256 bf16][Bpack 32768 bf16][red 128*128 f32]
  // partial (mtiles*4*128 f32 = 1.6MB) aliases staging (dead after agg).
  int*      rptr    = (int*)d_ws;
  int*      cnt     = rptr + (size_t)mtiles * RSTRIDE;
  int*      off     = cnt + mpad;
  unsigned* staging = (unsigned*)(off + mpad);
  short*    A       = (short*)(staging + (size_t)mtiles * CAP);
  short*    Bpack   = A + (size_t)mpad * 256;
  float*    red     = (float*)(Bpack + 32768);
  float*    partial = (float*)staging;  // alias

  hipMemsetAsync(rptr, 0, (size_t)mtiles * RSTRIDE * sizeof(int), stream);

  partition_kernel<<<(E + 255) / 256, 256, 0, stream>>>(ei, rptr, staging, E);

  bpack_kernel<<<16, 256, 0, stream>>>(Wl, Wr, Bpack);

  xcast_kernel<<<(mpad * 32 + 255) / 256, 256, 0, stream>>>(x, A, nnodes, mpad);

  compact_kernel<<<mtiles, 256, 0, stream>>>(rptr, staging, cnt, off);

  agg_kernel<<<(mpad + 3) / 4, 256, 0, stream>>>(cnt, off, staging, A,
                                                 nnodes, mpad);

  mfma_kernel<<<mtiles, 256, 0, stream>>>(A, Bpack, bl, partial, nnodes);

  red1_kernel<<<128, 256, 0, stream>>>(partial, mtiles * 4, red);
  red2_kernel<<<1, 256, 0, stream>>>(red, Wout, bout, (float*)d_out, nnodes);
}

// Round 8
// 128.367 us; speedup vs baseline: 6.0841x; 1.0484x over previous
//
#include <hip/hip_runtime.h>
#include <hip/hip_bf16.h>

#define DIM 128
#define NXCD 8
#define SUBCAP 224              // per (region,xcd) capacity: mean 128 + 8.5 sigma
#define REGCAP (NXCD * SUBCAP)  // 1792 entries per region
#define RSTRIDE 16              // ints per counter (64B: one line per counter)

typedef __attribute__((ext_vector_type(8))) short bf16x8;
typedef __attribute__((ext_vector_type(4))) float f32x4;
typedef __attribute__((ext_vector_type(4))) short short4v;

__device__ inline unsigned short f2bf(float f) {
  union { float f; unsigned u; } v; v.f = f;
  return (unsigned short)((v.u + 0x7FFFu + ((v.u >> 16) & 1u)) >> 16);
}
__device__ inline float lo_f(unsigned u) {
  union { unsigned u; float f; } v; v.u = u << 16; return v.f;
}
__device__ inline float hi_f(unsigned u) {
  union { unsigned u; float f; } v; v.u = u & 0xFFFF0000u; return v.f;
}

// ---------------------------------------------------------------------------
// K1: partition edges into 64-node dst-regions with XCD-LOCAL sub-lists.
// blockIdx.x&7 proxies the XCD (round-robin dispatch); each (region,xcd)
// sub-list is 14 exact cache lines filled monotonically by one XCD ->
// each line written back once (vs 12x cross-XCD bounce previously).
// Entry = (dst&63)<<16 | src  (src < 65536 for N=50000).
// ---------------------------------------------------------------------------
__global__ __launch_bounds__(256) void partition_kernel(
    const int* __restrict__ ei, int* __restrict__ rptr,
    unsigned* __restrict__ staging, int E) {
  int e = blockIdx.x * 256 + threadIdx.x;
  if (e >= E) return;
  const int xcd = blockIdx.x & (NXCD - 1);
  unsigned src = (unsigned)ei[e];
  int dst = ei[E + e];
  int r = dst >> 6;
  int slot = atomicAdd(&rptr[(r * NXCD + xcd) * RSTRIDE], 1);
  if (slot < SUBCAP)
    staging[(size_t)r * REGCAP + xcd * SUBCAP + slot] =
        ((unsigned)(dst & 63) << 16) | src;
}

// ---------------------------------------------------------------------------
// K2: per-region merge of 8 sub-lists + in-LDS counting sort -> dst-sorted
// src lists (in place at region*REGCAP, coalesced writeback) + per-node
// deg (cnt) and global offset (off). One block per region.
// ---------------------------------------------------------------------------
__global__ __launch_bounds__(256) void compact_kernel(
    const int* __restrict__ rptr, unsigned* __restrict__ staging,
    int* __restrict__ cnt, int* __restrict__ off) {
  __shared__ unsigned raw[REGCAP];
  __shared__ unsigned sorted[REGCAP];
  __shared__ int h[64];
  __shared__ int start[64];
  __shared__ int fill[64];
  __shared__ int scnt[NXCD];
  __shared__ int sub0[NXCD];
  const int region = blockIdx.x;
  const int tid = threadIdx.x;
  const size_t base = (size_t)region * REGCAP;

  if (tid < NXCD)
    scnt[tid] = min(rptr[(region * NXCD + tid) * RSTRIDE], SUBCAP);
  if (tid < 64) { h[tid] = 0; fill[tid] = 0; }
  __syncthreads();
  if (tid == 0) {
    int s = 0;
    for (int x = 0; x < NXCD; ++x) { sub0[x] = s; s += scnt[x]; }
  }
  __syncthreads();

  for (int x = 0; x < NXCD; ++x) {
    const int c = scnt[x];
    const int b = sub0[x];
    for (int i = tid; i < c; i += 256) {
      unsigned e = staging[base + x * SUBCAP + i];
      raw[b + i] = e;
      atomicAdd(&h[e >> 16], 1);
    }
  }
  __syncthreads();
  if (tid == 0) {
    int s = 0;
    for (int i = 0; i < 64; ++i) { start[i] = s; s += h[i]; }
  }
  __syncthreads();
  const int total = sub0[NXCD - 1] + scnt[NXCD - 1];
  for (int i = tid; i < total; i += 256) {
    unsigned e = raw[i];
    int d = (int)(e >> 16);
    int pos = start[d] + atomicAdd(&fill[d], 1);
    sorted[pos] = e & 0xFFFFu;  // keep only src
  }
  __syncthreads();
  for (int i = tid; i < total; i += 256) staging[base + i] = sorted[i];
  if (tid < 64) {
    int node = region * 64 + tid;
    cnt[node] = h[tid];
    off[node] = (int)base + start[tid];
  }
}

// ---------------------------------------------------------------------------
// K3: cast x -> bf16 into the x-half of A.  A layout: [mpad][256] bf16,
// k<128 = agg (written by agg_kernel), k>=128 = x.
// ---------------------------------------------------------------------------
__global__ __launch_bounds__(256) void xcast_kernel(
    const float* __restrict__ x, short* __restrict__ A, int nnodes, int mpad) {
  int t = blockIdx.x * 256 + threadIdx.x;
  int node = t >> 5;
  if (node >= mpad) return;
  int c = (t & 31) * 4;
  short4v o = (short4v){0, 0, 0, 0};
  if (node < nnodes) {
    float4 v = *reinterpret_cast<const float4*>(x + (size_t)node * DIM + c);
    o.x = (short)f2bf(v.x); o.y = (short)f2bf(v.y);
    o.z = (short)f2bf(v.z); o.w = (short)f2bf(v.w);
  }
  *reinterpret_cast<short4v*>(A + (size_t)node * 256 + 128 + c) = o;
}

// ---------------------------------------------------------------------------
// K4: mean-aggregation, one wave per node (50048 waves of TLP); gathers bf16
// x-rows from A's x-half (256B coalesced, 4-deep MLP), writes bf16 agg into
// A's agg-half.
// ---------------------------------------------------------------------------
__global__ __launch_bounds__(256) void agg_kernel(
    const int* __restrict__ cnt, const int* __restrict__ off,
    const unsigned* __restrict__ bucket, short* __restrict__ A,
    int nnodes, int mpad) {
  const int wid = (blockIdx.x * 256 + threadIdx.x) >> 6;
  const int lane = threadIdx.x & 63;
  if (wid >= mpad) return;
  unsigned* dst = reinterpret_cast<unsigned*>(A + (size_t)wid * 256) + lane;
  if (wid >= nnodes) { *dst = 0u; return; }
  const int deg  = __builtin_amdgcn_readfirstlane(cnt[wid]);
  const int base = __builtin_amdgcn_readfirstlane(off[wid]);
  const unsigned* xs = reinterpret_cast<const unsigned*>(A) + 64 + lane;

  float a0 = 0.f, b0 = 0.f, a1 = 0.f, b1 = 0.f;
  float a2 = 0.f, b2 = 0.f, a3 = 0.f, b3 = 0.f;
  int j = 0;
  for (; j + 3 < deg; j += 4) {
    const int s0 = __builtin_amdgcn_readfirstlane((int)bucket[base + j]);
    const int s1 = __builtin_amdgcn_readfirstlane((int)bucket[base + j + 1]);
    const int s2 = __builtin_amdgcn_readfirstlane((int)bucket[base + j + 2]);
    const int s3 = __builtin_amdgcn_readfirstlane((int)bucket[base + j + 3]);
    unsigned u0 = xs[(size_t)s0 * 128];
    unsigned u1 = xs[(size_t)s1 * 128];
    unsigned u2 = xs[(size_t)s2 * 128];
    unsigned u3 = xs[(size_t)s3 * 128];
    a0 += lo_f(u0); b0 += hi_f(u0);
    a1 += lo_f(u1); b1 += hi_f(u1);
    a2 += lo_f(u2); b2 += hi_f(u2);
    a3 += lo_f(u3); b3 += hi_f(u3);
  }
  for (; j < deg; ++j) {
    const int s0 = __builtin_amdgcn_readfirstlane((int)bucket[base + j]);
    unsigned u0 = xs[(size_t)s0 * 128];
    a0 += lo_f(u0); b0 += hi_f(u0);
  }
  const float r = 1.0f / fmaxf((float)deg, 1.0f);
  const float av = (a0 + a1 + a2 + a3) * r;
  const float bv = (b0 + b1 + b2 + b3) * r;
  *dst = (unsigned)f2bf(av) | ((unsigned)f2bf(bv) << 16);
}

// ---------------------------------------------------------------------------
// K5: pack B = [[Wl];[Wr]] (256x128) into MFMA fragment order
// ---------------------------------------------------------------------------
__global__ __launch_bounds__(256) void bpack_kernel(
    const float* __restrict__ Wl, const float* __restrict__ Wr,
    short* __restrict__ Bpack) {
  int t = blockIdx.x * 256 + threadIdx.x;
  if (t >= 4096) return;
  int lane = t & 63, nt = (t >> 6) & 7, ks = t >> 9;
  int c = nt * 16 + (lane & 15);
  int kb = ks * 32 + ((lane >> 4) << 3);
  bf16x8 o;
#pragma unroll
  for (int j = 0; j < 8; ++j) {
    int k = kb + j;
    float v = (k < DIM) ? Wl[k * DIM + c] : Wr[(k - DIM) * DIM + c];
    o[j] = (short)f2bf(v);
  }
  reinterpret_cast<bf16x8*>(Bpack)[(ks * 8 + nt) * 64 + lane] = o;
}

// ---------------------------------------------------------------------------
// K6: MFMA GEMM + fused bias/relu/row-masked column-sum -> per-wave partials
// ---------------------------------------------------------------------------
__global__ __launch_bounds__(256) void mfma_kernel(
    const short* __restrict__ A, const short* __restrict__ Bpack,
    const float* __restrict__ bl, float* __restrict__ partial, int nnodes) {
  __shared__ short a_lds[64 * 256];
  const int tid = threadIdx.x;
  const int wave = tid >> 6, lane = tid & 63;
  const int mt = blockIdx.x;
  const size_t abase = (size_t)mt * 64 * 256;

#pragma unroll
  for (int r = 0; r < 8; ++r) {
    int i = tid + 256 * r;
    int row = i >> 5, kc = i & 31;
    bf16x8 v = *reinterpret_cast<const bf16x8*>(A + abase + row * 256 + kc * 8);
    int byte = (row * 512 + kc * 16) ^ ((row & 7) << 4);
    *reinterpret_cast<bf16x8*>(reinterpret_cast<char*>(a_lds) + byte) = v;
  }
  __syncthreads();

  f32x4 acc[8];
#pragma unroll
  for (int nt = 0; nt < 8; ++nt) acc[nt] = (f32x4){0.f, 0.f, 0.f, 0.f};

  const int arow = wave * 16 + (lane & 15);
  const int kgrp = lane >> 4;
  const bf16x8* Bp = reinterpret_cast<const bf16x8*>(Bpack);

#pragma unroll
  for (int ks = 0; ks < 8; ++ks) {
    int byte = (arow * 512 + (ks * 32 + kgrp * 8) * 2) ^ ((arow & 7) << 4);
    bf16x8 a = *reinterpret_cast<const bf16x8*>(reinterpret_cast<char*>(a_lds) + byte);
#pragma unroll
    for (int nt = 0; nt < 8; ++nt) {
      bf16x8 b = Bp[(ks * 8 + nt) * 64 + lane];
      acc[nt] = __builtin_amdgcn_mfma_f32_16x16x32_bf16(a, b, acc[nt], 0, 0, 0);
    }
  }

  const int col16 = lane & 15;
  const int rowbase = mt * 64 + wave * 16 + kgrp * 4;
#pragma unroll
  for (int nt = 0; nt < 8; ++nt) {
    const int c = nt * 16 + col16;
    const float bb = bl[c];
    float s = 0.f;
#pragma unroll
    for (int rg = 0; rg < 4; ++rg) {
      float v = fmaxf(acc[nt][rg] + bb, 0.f);
      s += (rowbase + rg < nnodes) ? v : 0.f;
    }
    s += __shfl_xor(s, 16);
    s += __shfl_xor(s, 32);
    if (kgrp == 0) partial[((size_t)mt * 4 + wave) * DIM + c] = s;
  }
}

// ---------------------------------------------------------------------------
// K7a: parallel row-reduction of partial [nrows][128] -> red[128][128]
// ---------------------------------------------------------------------------
__global__ __launch_bounds__(256) void red1_kernel(
    const float* __restrict__ partial, int nrows, float* __restrict__ red) {
  __shared__ float tmp[128];
  const int c = threadIdx.x & 127;
  const int half = threadIdx.x >> 7;
  const int chunk = (nrows + 127) / 128;
  const int r0 = blockIdx.x * chunk;
  const int r1 = min(r0 + chunk, nrows);
  float s = 0.f;
  for (int r = r0 + half; r < r1; r += 2) s += partial[(size_t)r * DIM + c];
  if (half) tmp[c] = s;
  __syncthreads();
  if (!half) red[(size_t)blockIdx.x * DIM + c] = s + tmp[c];
}

// ---------------------------------------------------------------------------
// K7b: sum red's 128 rows, dot with W_out, scale, add bias.
// ---------------------------------------------------------------------------
__global__ __launch_bounds__(256) void red2_kernel(
    const float* __restrict__ red, const float* __restrict__ Wout,
    const float* __restrict__ bout, float* __restrict__ out, int nnodes) {
  __shared__ float tmp[128];
  __shared__ float prod[128];
  const int c = threadIdx.x & 127;
  const int half = threadIdx.x >> 7;
  float s = 0.f;
  for (int r = half; r < 128; r += 2) s += red[(size_t)r * DIM + c];
  if (half) tmp[c] = s;
  __syncthreads();
  if (!half) prod[c] = (s + tmp[c]) * Wout[c];
  __syncthreads();
  if (threadIdx.x == 0) {
    float v = 0.f;
    for (int i = 0; i < 128; ++i) v += prod[i];
    out[0] = v / (float)nnodes + bout[0];
  }
}

extern "C" void kernel_launch(void* const* d_in, const int* in_sizes, int n_in,
                              void* d_out, int out_size, void* d_ws, size_t ws_size,
                              hipStream_t stream) {
  const float* x    = (const float*)d_in[0];   // x_ligand [N,128]
  const int*   ei   = (const int*)d_in[4];     // ei_ll [2,E]
  const float* Wl   = (const float*)d_in[11];  // Wl_ll [128,128]
  const float* bl   = (const float*)d_in[12];  // bl_ll [128]
  const float* Wr   = (const float*)d_in[13];  // Wr_ll [128,128]
  const float* Wout = (const float*)d_in[14];  // W_out [128,1]
  const float* bout = (const float*)d_in[15];  // b_out [1]

  const int nnodes = in_sizes[0] / DIM;
  const int E = in_sizes[4] / 2;
  const int mtiles = (nnodes + 63) / 64;   // 782 == #regions
  const int mpad = mtiles * 64;            // 50048

  // ws layout: [rptr mtiles*8*RSTRIDE][cnt mpad][off mpad]
  //            [staging mtiles*REGCAP u32][A mpad*256 bf16][Bpack 32768 bf16]
  //            [red 128*128 f32]
  // partial (mtiles*4*128 f32 = 1.6MB) aliases staging (dead after agg).
  int*      rptr    = (int*)d_ws;
  int*      cnt     = rptr + (size_t)mtiles * NXCD * RSTRIDE;
  int*      off     = cnt + mpad;
  unsigned* staging = (unsigned*)(off + mpad);
  short*    A       = (short*)(staging + (size_t)mtiles * REGCAP);
  short*    Bpack   = A + (size_t)mpad * 256;
  float*    red     = (float*)(Bpack + 32768);
  float*    partial = (float*)staging;  // alias

  hipMemsetAsync(rptr, 0, (size_t)mtiles * NXCD * RSTRIDE * sizeof(int), stream);

  partition_kernel<<<(E + 255) / 256, 256, 0, stream>>>(ei, rptr, staging, E);

  bpack_kernel<<<16, 256, 0, stream>>>(Wl, Wr, Bpack);

  xcast_kernel<<<(mpad * 32 + 255) / 256, 256, 0, stream>>>(x, A, nnodes, mpad);

  compact_kernel<<<mtiles, 256, 0, stream>>>(rptr, staging, cnt, off);

  agg_kernel<<<(mpad + 3) / 4, 256, 0, stream>>>(cnt, off, staging, A,
                                                 nnodes, mpad);

  mfma_kernel<<<mtiles, 256, 0, stream>>>(A, Bpack, bl, partial, nnodes);

  red1_kernel<<<128, 256, 0, stream>>>(partial, mtiles * 4, red);
  red2_kernel<<<1, 256, 0, stream>>>(red, Wout, bout, (float*)d_out, nnodes);
}